// Round 4
// baseline (720.788 us; speedup 1.0000x reference)
//
#include <hip/hip_runtime.h>
#include <math.h>

// MoLoRARouter: logits = x[16384,4096] @ gate_w[64,4096]^T (fp32) -> softmax
// -> top-2 -> renorm.  fp32 emulated as split-2 fp16 MFMA:
//   v = h + l/2048, logit = hh + (hl+lh)/2048 + ll/2048^2  (error ~1e-6).
// R4 structure: NO LDS staging, NO main-loop barriers. MFMA A/B fragments are
// loaded straight from global (A[m=ln15][k=quad*8+j] = 8 contiguous floats of
// one row; a wave covers 16 rows x 128 B segments -> fully coalesced).
// gate_w (1 MB) is L2-resident; x streams once from HBM. Depth-2 register
// pipeline; BM=32, grid=512, launch_bounds(256,2) -> 2 blocks/CU, 8 waves/CU.
// w1 = 1/(1+exp(l2-l1)), w2 = 1-w1. Indices stored as float.

typedef _Float16 half8 __attribute__((ext_vector_type(8)));
typedef float floatx4 __attribute__((ext_vector_type(4)));

constexpr int Hdim = 4096;
constexpr int Edim = 64;
constexpr int BM   = 32;          // tokens per block
constexpr int BK   = 32;          // K-chunk (floats) = one MFMA K
constexpr int NKT  = Hdim / BK;   // 128 chunks
constexpr int NTOK = 16384;
constexpr int PSTR = 68;          // logits row stride (floats)
constexpr float SCL  = 2048.0f;
constexpr float ISCL = 1.0f / 2048.0f;

struct Chunk { float4 a0, a1, b00, b01, b10, b11; };

__device__ __forceinline__ void load_chunk(const float* __restrict__ xA,
                                           const float* __restrict__ w0,
                                           const float* __restrict__ w1,
                                           int k, Chunk& c) {
    c.a0  = *(const float4*)(xA + k);
    c.a1  = *(const float4*)(xA + k + 4);
    c.b00 = *(const float4*)(w0 + k);
    c.b01 = *(const float4*)(w0 + k + 4);
    c.b10 = *(const float4*)(w1 + k);
    c.b11 = *(const float4*)(w1 + k + 4);
}

__device__ __forceinline__ void cvt8(const float4& u, const float4& v,
                                     half8& h, half8& l) {
    const float* pu = (const float*)&u;
    const float* pv = (const float*)&v;
    #pragma unroll
    for (int c = 0; c < 4; ++c) {
        _Float16 hh = (_Float16)pu[c];
        h[c] = hh;
        l[c] = (_Float16)((pu[c] - (float)hh) * SCL);
        hh = (_Float16)pv[c];
        h[4 + c] = hh;
        l[4 + c] = (_Float16)((pv[c] - (float)hh) * SCL);
    }
}

__device__ __forceinline__ void do_mfma(const Chunk& c, floatx4 accm[2],
                                        floatx4 accc[2], floatx4 accl[2]) {
    half8 ah, al, bh0, bl0, bh1, bl1;
    cvt8(c.a0,  c.a1,  ah,  al);
    cvt8(c.b00, c.b01, bh0, bl0);
    cvt8(c.b10, c.b11, bh1, bl1);
    accm[0] = __builtin_amdgcn_mfma_f32_16x16x32_f16(ah, bh0, accm[0], 0, 0, 0);
    accc[0] = __builtin_amdgcn_mfma_f32_16x16x32_f16(ah, bl0, accc[0], 0, 0, 0);
    accc[0] = __builtin_amdgcn_mfma_f32_16x16x32_f16(al, bh0, accc[0], 0, 0, 0);
    accl[0] = __builtin_amdgcn_mfma_f32_16x16x32_f16(al, bl0, accl[0], 0, 0, 0);
    accm[1] = __builtin_amdgcn_mfma_f32_16x16x32_f16(ah, bh1, accm[1], 0, 0, 0);
    accc[1] = __builtin_amdgcn_mfma_f32_16x16x32_f16(ah, bl1, accc[1], 0, 0, 0);
    accc[1] = __builtin_amdgcn_mfma_f32_16x16x32_f16(al, bh1, accc[1], 0, 0, 0);
    accl[1] = __builtin_amdgcn_mfma_f32_16x16x32_f16(al, bl1, accl[1], 0, 0, 0);
}

__global__ __launch_bounds__(256, 2)
void router_kernel(const float* __restrict__ x,
                   const float* __restrict__ gw,
                   float* __restrict__ out)
{
    __shared__ float slg[BM * PSTR];   // 8.7 KB — epilogue only

    const int tid  = threadIdx.x;
    const int t0   = blockIdx.x * BM;
    const int wv   = tid >> 6, lane = tid & 63;
    const int ln15 = lane & 15, quad = lane >> 4;
    const int th   = (wv >> 1) * 16;   // token base: waves {0,1}->0, {2,3}->16
    const int eh   = (wv & 1) * 32;    // expert base: 0 or 32

    // fragment base pointers (A: one token row; B: two expert rows)
    const float* xA = x  + (size_t)(t0 + th + ln15) * Hdim + quad * 8;
    const float* w0 = gw + (size_t)(eh + ln15)      * Hdim + quad * 8;
    const float* w1 = gw + (size_t)(eh + 16 + ln15) * Hdim + quad * 8;

    floatx4 accm[2], accc[2], accl[2];
    #pragma unroll
    for (int n = 0; n < 2; ++n) {
        accm[n] = (floatx4)0.0f;
        accc[n] = (floatx4)0.0f;
        accl[n] = (floatx4)0.0f;
    }

    // depth-2 register pipeline, no barriers
    Chunk c0, c1;
    load_chunk(xA, w0, w1, 0,  c0);
    load_chunk(xA, w0, w1, BK, c1);

    for (int kt = 0; kt < NKT; kt += 2) {
        {
            Chunk t = c0;                      // consume chunk kt
            const int kn = (kt + 2 < NKT) ? (kt + 2) * BK : kt * BK;
            load_chunk(xA, w0, w1, kn, c0);    // prefetch kt+2
            do_mfma(t, accm, accc, accl);
        }
        {
            Chunk t = c1;                      // consume chunk kt+1
            const int kn = (kt + 3 < NKT) ? (kt + 3) * BK : kt * BK;
            load_chunk(xA, w0, w1, kn, c1);    // prefetch kt+3
            do_mfma(t, accm, accc, accl);
        }
    }

    // ---- epilogue: combine split terms -> LDS -> per-token top-2 ----
    #pragma unroll
    for (int nt = 0; nt < 2; ++nt)
        #pragma unroll
        for (int i = 0; i < 4; ++i) {
            const float v = accm[nt][i] + accc[nt][i] * ISCL
                          + accl[nt][i] * (ISCL * ISCL);
            const int r = th + quad * 4 + i;      // D: row = quad*4+reg
            const int cc = eh + nt * 16 + ln15;   // D: col = lane&15
            slg[r * PSTR + cc] = v;
        }
    __syncthreads();

    if (tid < BM) {
        const float* row = &slg[tid * PSTR];
        float m1 = -INFINITY, m2 = -INFINITY;
        int i1 = 0, i2 = 0;
        for (int e = 0; e < Edim; ++e) {
            float v = row[e];
            if (v > m1) { m2 = m1; i2 = i1; m1 = v; i1 = e; }  // strict >: lower idx wins ties
            else if (v > m2) { m2 = v; i2 = e; }
        }
        const float r   = expf(m2 - m1);
        const float inv = 1.f / (1.f + r);
        const int t = t0 + tid;
        float* ow = out + 2 * (size_t)t;
        ow[0] = inv;
        ow[1] = r * inv;
        float* oi = out + 2 * (size_t)NTOK + 2 * (size_t)t;
        oi[0] = (float)i1;
        oi[1] = (float)i2;
    }
}

extern "C" void kernel_launch(void* const* d_in, const int* in_sizes, int n_in,
                              void* d_out, int out_size, void* d_ws, size_t ws_size,
                              hipStream_t stream) {
    const float* x  = (const float*)d_in[0];   // [4,4096,4096] fp32
    const float* gw = (const float*)d_in[1];   // [64,4096] fp32
    float* out = (float*)d_out;                // weights(32768) ++ indices(32768)
    dim3 grid(NTOK / BM), block(256);          // 512 blocks -> 2 blocks/CU
    hipLaunchKernelGGL(router_kernel, grid, block, 0, stream, x, gw, out);
}